// Round 2
// baseline (250.206 us; speedup 1.0000x reference)
//
#include <hip/hip_runtime.h>

// out[n, t] = sum_{j <= t} W[t, j] * x[n, j] + b[t]
// B = 1048576, T = 32, fp32. Round-1 was LDS-pipe-bound on 528 wave-uniform
// ds_read_b32 W broadcasts (51 LDS-cyc/row == measured 90 us). Fix: 2 rows per
// thread (W read amortized over 2 rows) + W read as float4 (b128), j-chunked.

constexpr int T     = 32;
constexpr int ROWS  = 512;        // rows per block (256 threads x 2 rows)
constexpr int RSTR  = T + 1;      // padded LDS row stride -> only 2-way (free) aliasing

__global__ __launch_bounds__(256, 2) void triu_kernel(
    const float* __restrict__ x, const float* __restrict__ W,
    const float* __restrict__ b, float* __restrict__ out)
{
    __shared__ float sW[T * T];         // 4 KiB, row-major, b128-readable (16B aligned)
    __shared__ float sb[T];
    __shared__ float sX[ROWS * RSTR];   // 512*33*4 = 66 KiB

    const int tid = threadIdx.x;

    for (int i = tid; i < T * T; i += 256) sW[i] = W[i];
    if (tid < T) sb[tid] = b[tid];

    const long long base = (long long)blockIdx.x * (ROWS * T);
    const float4* __restrict__ x4 = reinterpret_cast<const float4*>(x + base);

    // Coalesced staging: 16 float4 per thread into padded LDS.
    #pragma unroll
    for (int it = 0; it < (ROWS * T) / (256 * 4); ++it) {   // 16 iters
        const int idx = it * 256 + tid;
        const float4 v = x4[idx];
        const int r = idx >> 3;
        const int c = (idx & 7) << 2;
        float* p = &sX[r * RSTR + c];
        p[0] = v.x; p[1] = v.y; p[2] = v.z; p[3] = v.w;
    }
    __syncthreads();

    float acc0[T], acc1[T];
    #pragma unroll
    for (int t = 0; t < T; ++t) { const float bt = sb[t]; acc0[t] = bt; acc1[t] = bt; }

    const float* __restrict__ r0 = &sX[tid * RSTR];
    const float* __restrict__ r1 = &sX[(tid + 256) * RSTR];

    #pragma unroll
    for (int jc = 0; jc < 8; ++jc) {
        // x chunk j = 4jc .. 4jc+3 for both rows (b32 reads, conflict-free stride 33)
        float a0[4], a1[4];
        #pragma unroll
        for (int k = 0; k < 4; ++k) { a0[k] = r0[4 * jc + k]; a1[k] = r1[4 * jc + k]; }

        // Diagonal 4x4 block: t = 4jc+k uses j = 4jc .. 4jc+k (read b128, use valid lanes)
        #pragma unroll
        for (int k = 0; k < 4; ++k) {
            const int t = 4 * jc + k;
            const float4 w4 = *reinterpret_cast<const float4*>(&sW[t * T + 4 * jc]);
            const float wv[4] = {w4.x, w4.y, w4.z, w4.w};
            #pragma unroll
            for (int j = 0; j <= k; ++j) {
                acc0[t] = fmaf(wv[j], a0[j], acc0[t]);
                acc1[t] = fmaf(wv[j], a1[j], acc1[t]);
            }
        }
        // Full blocks: t = 4jc+4 .. 31, all 4 j's valid -> one b128 + 8 fma
        #pragma unroll
        for (int t = 4 * jc + 4; t < T; ++t) {
            const float4 w4 = *reinterpret_cast<const float4*>(&sW[t * T + 4 * jc]);
            acc0[t] = fmaf(w4.x, a0[0], acc0[t]);
            acc0[t] = fmaf(w4.y, a0[1], acc0[t]);
            acc0[t] = fmaf(w4.z, a0[2], acc0[t]);
            acc0[t] = fmaf(w4.w, a0[3], acc0[t]);
            acc1[t] = fmaf(w4.x, a1[0], acc1[t]);
            acc1[t] = fmaf(w4.y, a1[1], acc1[t]);
            acc1[t] = fmaf(w4.z, a1[2], acc1[t]);
            acc1[t] = fmaf(w4.w, a1[3], acc1[t]);
        }
    }

    // Write results back over own rows (no cross-thread hazard), then coalesced store.
    float* w0 = &sX[tid * RSTR];
    float* w1 = &sX[(tid + 256) * RSTR];
    #pragma unroll
    for (int t = 0; t < T; ++t) { w0[t] = acc0[t]; w1[t] = acc1[t]; }
    __syncthreads();

    float4* __restrict__ o4 = reinterpret_cast<float4*>(out + base);
    #pragma unroll
    for (int it = 0; it < (ROWS * T) / (256 * 4); ++it) {   // 16 iters
        const int idx = it * 256 + tid;
        const int r = idx >> 3;
        const int c = (idx & 7) << 2;
        const float* p = &sX[r * RSTR + c];
        o4[idx] = make_float4(p[0], p[1], p[2], p[3]);
    }
}

extern "C" void kernel_launch(void* const* d_in, const int* in_sizes, int n_in,
                              void* d_out, int out_size, void* d_ws, size_t ws_size,
                              hipStream_t stream) {
    const float* x  = (const float*)d_in[0];   // [B, 32]
    const float* W  = (const float*)d_in[1];   // [32, 32] (lower-tri used)
    const float* b  = (const float*)d_in[2];   // [32]
    float* out      = (float*)d_out;           // [B, 32]

    const int batch = in_sizes[0] / T;         // 1048576
    const int grid  = batch / ROWS;            // 2048 blocks
    triu_kernel<<<grid, 256, 0, stream>>>(x, W, b, out);
}

// Round 3
// 242.407 us; speedup vs baseline: 1.0322x; 1.0322x over previous
//
#include <hip/hip_runtime.h>

// out[n, t] = sum_{j <= t} W[t, j] * x[n, j] + b[t]
// B = 1048576, T = 32, fp32. R1 was LDS-pipe-bound (528 b32 W broadcasts = 59
// LDS-cyc/row = 90 us). R2 (2 rows/thread, 70KB LDS) collapsed occupancy to
// 2 waves/SIMD + spilled. R3: W/b read via wave-uniform global loads -> scalar
// s_load through K$ (SMEM pipe, 4KB fully cached), zero LDS cost for W; x stays
// LDS-staged (coalesced, stride-33 conflict-free); 1 row/thread; 33.8KB LDS ->
// 4 blocks/CU.

constexpr int T    = 32;
constexpr int ROWS = 256;         // rows per block == block size
constexpr int RSTR = T + 1;       // stride 33: compute reads bank=(lane+j)%32, conflict-free

__global__ __launch_bounds__(256) void triu_kernel(
    const float* __restrict__ x, const float* __restrict__ W,
    const float* __restrict__ b, float* __restrict__ out)
{
    __shared__ float sX[ROWS * RSTR];   // 33792 B

    const int tid = threadIdx.x;
    const long long base = (long long)blockIdx.x * (ROWS * T);

    // Coalesced float4 staging into padded LDS.
    const float4* __restrict__ x4 = reinterpret_cast<const float4*>(x + base);
    #pragma unroll
    for (int it = 0; it < (ROWS * T) / (256 * 4); ++it) {   // 8 iters
        const int idx = it * 256 + tid;
        const float4 v = x4[idx];
        const int r = idx >> 3;
        const int c = (idx & 7) << 2;
        float* p = &sX[r * RSTR + c];
        p[0] = v.x; p[1] = v.y; p[2] = v.z; p[3] = v.w;
    }
    __syncthreads();

    // Bias init: uniform address -> scalar loads (K$), v_mov broadcast.
    float acc[T];
    #pragma unroll
    for (int t = 0; t < T; ++t) acc[t] = b[t];

    const float* __restrict__ myrow = &sX[tid * RSTR];

    #pragma unroll
    for (int jc = 0; jc < 8; ++jc) {
        // x chunk j = 4jc .. 4jc+3 (b32 LDS reads, conflict-free)
        float a[4];
        #pragma unroll
        for (int k = 0; k < 4; ++k) a[k] = myrow[4 * jc + k];

        // Diagonal 4x4 block: t = 4jc+k uses j = 4jc..4jc+k. W addr is
        // wave-uniform + compile-time offset -> s_load_dwordx4 via K$.
        #pragma unroll
        for (int k = 0; k < 4; ++k) {
            const int t = 4 * jc + k;
            const float4 w4 = *reinterpret_cast<const float4*>(&W[t * T + 4 * jc]);
            const float wv[4] = {w4.x, w4.y, w4.z, w4.w};
            #pragma unroll
            for (int j = 0; j <= k; ++j)
                acc[t] = fmaf(wv[j], a[j], acc[t]);
        }
        // Full blocks below the diagonal: one dwordx4 + 4 fma per t.
        #pragma unroll
        for (int t = 4 * jc + 4; t < T; ++t) {
            const float4 w4 = *reinterpret_cast<const float4*>(&W[t * T + 4 * jc]);
            acc[t] = fmaf(w4.x, a[0], acc[t]);
            acc[t] = fmaf(w4.y, a[1], acc[t]);
            acc[t] = fmaf(w4.z, a[2], acc[t]);
            acc[t] = fmaf(w4.w, a[3], acc[t]);
        }
    }

    // Overwrite own row with result, then coalesced float4 stores.
    float* wr = &sX[tid * RSTR];
    #pragma unroll
    for (int t = 0; t < T; ++t) wr[t] = acc[t];
    __syncthreads();

    float4* __restrict__ o4 = reinterpret_cast<float4*>(out + base);
    #pragma unroll
    for (int it = 0; it < 8; ++it) {
        const int idx = it * 256 + tid;
        const int r = idx >> 3;
        const int c = (idx & 7) << 2;
        const float* p = &sX[r * RSTR + c];
        o4[idx] = make_float4(p[0], p[1], p[2], p[3]);
    }
}

extern "C" void kernel_launch(void* const* d_in, const int* in_sizes, int n_in,
                              void* d_out, int out_size, void* d_ws, size_t ws_size,
                              hipStream_t stream) {
    const float* x  = (const float*)d_in[0];   // [B, 32]
    const float* W  = (const float*)d_in[1];   // [32, 32] (lower-tri used)
    const float* b  = (const float*)d_in[2];   // [32]
    float* out      = (float*)d_out;           // [B, 32]

    const int batch = in_sizes[0] / T;         // 1048576
    const int grid  = batch / ROWS;            // 4096 blocks
    triu_kernel<<<grid, 256, 0, stream>>>(x, W, b, out);
}